// Round 1
// baseline (444.866 us; speedup 1.0000x reference)
//
#include <hip/hip_runtime.h>

// LoRA forward, fused, all fp32:
//   out[m,n] = 2 * sum_r (sum_k x[m,k] * B[k,r]) * A[r,n]
// x: [16384, 4096] f32, B: [4096, 8] f32, A: [8, 4096] f32, out: [16384, 4096] f32.
// Memory-bound in principle (512 MiB traffic, ~85 us roofline); previous version
// (445 us) was latency-bound: 48-shfl serial butterfly per row + 1-row prefetch.
// This version: 17-shfl folding reduce + depth-2 prefetch ping-pong.

#define NT      256
#define ROWS    16
#define KDIM    4096
#define NDIM    4096
#define M_TOTAL 16384

typedef __attribute__((ext_vector_type(4))) float float4v;

__global__ __launch_bounds__(NT, 2) void lora_fused(
    const float* __restrict__ x,
    const float* __restrict__ A,
    const float* __restrict__ B,
    float* __restrict__ out)
{
    __shared__ float part[ROWS][4][8];  // per-wave rank partials
    __shared__ float tl[ROWS][8];       // final 2*t[row][r]

    const int t = threadIdx.x;
    const int lane = t & 63;
    const int wave = t >> 6;
    const long m_base = (long)blockIdx.x * ROWS;

    // frag[j][r]: phase 1 = B[k(j)][r]; phase 2 (reused) = A[r][n(j)].
    // j = 4*q + i  ->  k(j) = n(j) = q*1024 + 4*t + i   (q,i in 0..3)
    float frag[16][8];

    {   // B fragment: 16 rows of B, each 8 f32 = two float4.
        const float4v* Bv = (const float4v*)B;
#pragma unroll
        for (int q = 0; q < 4; ++q)
#pragma unroll
            for (int i = 0; i < 4; ++i) {
                const int k = q * 1024 + 4 * t + i;
                float4v b0 = Bv[2 * k];
                float4v b1 = Bv[2 * k + 1];
                const int j = 4 * q + i;
#pragma unroll
                for (int r = 0; r < 4; ++r) {
                    frag[j][r]     = b0[r];
                    frag[j][4 + r] = b1[r];
                }
            }
    }

    // ---------------- Phase 1: t = x @ B ----------------
    // Two row buffers, ping-pong; prefetch distance 2.
    float4v c0[4], c1[4];
    {
        const float4v* x0 = (const float4v*)(x + m_base * KDIM);
        const float4v* x1 = (const float4v*)(x + (m_base + 1) * KDIM);
#pragma unroll
        for (int q = 0; q < 4; ++q) {
            c0[q] = x0[q * 256 + t];
            c1[q] = x1[q * 256 + t];
        }
    }

    auto p1_body = [&](float4v (&cb)[4], int rr) {
        // FMA: 16 k-values * 8 ranks
        float acc[8];
#pragma unroll
        for (int r = 0; r < 8; ++r) acc[r] = 0.0f;
#pragma unroll
        for (int q = 0; q < 4; ++q)
#pragma unroll
            for (int i = 0; i < 4; ++i) {
                const float xv = cb[q][i];
                const int j = 4 * q + i;
#pragma unroll
                for (int r = 0; r < 8; ++r)
                    acc[r] = fmaf(xv, frag[j][r], acc[r]);
            }

        // Prefetch row rr+2 into the buffer we just consumed (WAR-safe:
        // all reads of cb are above). VMEM overlaps the DS-reduce below
        // plus the whole next iteration.
        const int nr = rr + 2;
        if (nr < ROWS) {
            const float4v* xn = (const float4v*)(x + (m_base + nr) * KDIM);
#pragma unroll
            for (int q = 0; q < 4; ++q) cb[q] = xn[q * 256 + t];
        }

        // Folding reduce: 17 shfls instead of 48 (full allreduce is overkill —
        // only one lane per r needs the sum; broadcast happens via LDS later).
        // Stage A (xor 32): 8 values -> 4 per lane.
        float s[8];
#pragma unroll
        for (int r = 0; r < 8; ++r) s[r] = __shfl_xor(acc[r], 32, 64);
        const bool b5 = (lane & 32) != 0;
        float v[4];
#pragma unroll
        for (int j = 0; j < 4; ++j)
            v[j] = b5 ? (acc[4 + j] + s[4 + j]) : (acc[j] + s[j]);
        // Stage B (xor 16): 4 -> 2.
        float sb[4];
#pragma unroll
        for (int j = 0; j < 4; ++j) sb[j] = __shfl_xor(v[j], 16, 64);
        const bool b4 = (lane & 16) != 0;
        float w0 = b4 ? (v[2] + sb[2]) : (v[0] + sb[0]);
        float w1 = b4 ? (v[3] + sb[3]) : (v[1] + sb[1]);
        // Stage C (xor 8): 2 -> 1.
        float sc0 = __shfl_xor(w0, 8, 64);
        float sc1 = __shfl_xor(w1, 8, 64);
        const bool b3 = (lane & 8) != 0;
        float u = b3 ? (w1 + sc1) : (w0 + sc0);
        // Stages D-F: reduce across lane bits 2..0.
        u += __shfl_xor(u, 4, 64);
        u += __shfl_xor(u, 2, 64);
        u += __shfl_xor(u, 1, 64);
        // Lane l (l&7)==0 holds the full 64-lane sum for
        // r = 4*bit5 + 2*bit4 + bit3.
        if ((lane & 7) == 0) {
            const int r = (((lane >> 5) & 1) << 2) | (((lane >> 4) & 1) << 1) |
                          ((lane >> 3) & 1);
            part[rr][wave][r] = u;
        }
    };

#pragma unroll 1
    for (int rp = 0; rp < ROWS; rp += 2) {
        p1_body(c0, rp);
        p1_body(c1, rp + 1);
    }

    __syncthreads();
    if (t < ROWS * 8) {
        const int rr = t >> 3, r = t & 7;
        tl[rr][r] = 2.0f * (part[rr][0][r] + part[rr][1][r] +
                            part[rr][2][r] + part[rr][3][r]);
    }

    {   // A fragment into the same register array (L2-resident, 128 KiB)
        const float4v* Av = (const float4v*)A;
#pragma unroll
        for (int r = 0; r < 8; ++r)
#pragma unroll
            for (int q = 0; q < 4; ++q) {
                float4v a = Av[r * 1024 + q * 256 + t];
#pragma unroll
                for (int i = 0; i < 4; ++i)
                    frag[4 * q + i][r] = a[i];
            }
    }
    __syncthreads();

    // ---------------- Phase 2: out = (2t) @ A ----------------
#pragma unroll 2
    for (int rr = 0; rr < ROWS; ++rr) {
        float tv[8];
#pragma unroll
        for (int r = 0; r < 8; ++r) tv[r] = tl[rr][r];  // LDS broadcast

        float4v* orow = (float4v*)(out + (m_base + rr) * NDIM);
#pragma unroll
        for (int q = 0; q < 4; ++q) {
            float4v o;
#pragma unroll
            for (int i = 0; i < 4; ++i) {
                float s2 = 0.0f;
#pragma unroll
                for (int r = 0; r < 8; ++r)
                    s2 = fmaf(tv[r], frag[4 * q + i][r], s2);
                o[i] = s2;
            }
            orow[q * 256 + t] = o;
        }
    }
}

extern "C" void kernel_launch(void* const* d_in, const int* in_sizes, int n_in,
                              void* d_out, int out_size, void* d_ws, size_t ws_size,
                              hipStream_t stream) {
    const float* x = (const float*)d_in[0];  // [4,4096,4096] -> [16384,4096]
    const float* A = (const float*)d_in[1];  // [8,4096]
    const float* B = (const float*)d_in[2];  // [4096,8]
    float* out = (float*)d_out;

    (void)in_sizes; (void)n_in; (void)out_size; (void)d_ws; (void)ws_size;

    dim3 grid(M_TOTAL / ROWS);
    lora_fused<<<grid, NT, 0, stream>>>(x, A, B, out);
}